// Round 4
// baseline (232.500 us; speedup 1.0000x reference)
//
#include <hip/hip_runtime.h>
#include <math.h>

constexpr int K = 512;
constexpr int D = 64;
constexpr int HW = 64 * 64;                      // 4096
constexpr int NPIX = 131072;
constexpr long long NELEM = (long long)NPIX * D; // 8388608
constexpr float BETA = 0.25f;
constexpr int NBLK = NPIX / 256;                 // 512 blocks

typedef __attribute__((ext_vector_type(8))) short short8;
typedef __attribute__((ext_vector_type(16))) float f32x16;

__device__ inline unsigned short bf16rne(float x) {
    unsigned u = __float_as_uint(x);
    unsigned r = (u + 0x7FFFu + ((u >> 16) & 1u)) >> 16;
    return (unsigned short)r;
}

__device__ inline void async_cp16(const void* g, void* l) {
    __builtin_amdgcn_global_load_lds(
        (const __attribute__((address_space(1))) void*)g,
        (__attribute__((address_space(3))) void*)l, 16, 0, 0);
}

// E[n][k] -> bf16 hi/lo of -2E in MFMA-B frag order + exact fp32 ee[n].
// Also zeroes counts / sse / ticket (replaces the memset dispatch).
__global__ __launch_bounds__(256) void prep_kernel(
    const float* __restrict__ E, float* __restrict__ ee,
    unsigned short* __restrict__ ebhi, unsigned short* __restrict__ eblo,
    unsigned int* __restrict__ counts, float* __restrict__ sse,
    unsigned int* __restrict__ ticket) {
    int gid = blockIdx.x * 256 + threadIdx.x;   // 0..32767
    if (gid < K) counts[gid] = 0u;
    if (gid == K) { *sse = 0.f; *ticket = 0u; }
    int n = gid >> 6, k = gid & 63;
    float v = E[gid];
    float a = v * v;
#pragma unroll
    for (int off = 32; off > 0; off >>= 1) a += __shfl_down(a, off, 64);
    if ((threadIdx.x & 63) == 0) ee[n] = a;
    float m2 = -2.f * v;
    unsigned short hi = bf16rne(m2);
    unsigned short lo = bf16rne(m2 - __uint_as_float((unsigned)hi << 16));
    int idx = ((n >> 5) * 4 + (k >> 4)) * 512 + ((k >> 3) & 1) * 256 + (n & 31) * 8 + (k & 7);
    ebhi[idx] = hi;
    eblo[idx] = lo;
}

__global__ __launch_bounds__(256, 3) void vq_mfma(
    const float* __restrict__ z, const float* __restrict__ E,
    const float* __restrict__ ee, const unsigned short* __restrict__ ebhi,
    const unsigned short* __restrict__ eblo, float* __restrict__ out,
    int out_size, float* __restrict__ sse_acc,
    unsigned int* __restrict__ counts, unsigned int* __restrict__ ticket) {

    __shared__ __align__(16) unsigned short sbh[8192];  // 16 KB: 128-code chunk (hi)
    __shared__ __align__(16) unsigned short sbl[8192];  // 16 KB: (lo)
    __shared__ int bks[256];
    __shared__ unsigned int hcnt[K];
    __shared__ float red[4];
    __shared__ int sflag;

    const int tid = threadIdx.x;
    const int wave = tid >> 6;
    const int lane = tid & 63;
    const int ln = lane & 31;
    const int half = lane >> 5;
    const int wb = wave * 64;

    const int p0 = blockIdx.x * 256;
    const int b = p0 >> 12;
    const int s0 = p0 & (HW - 1);

    hcnt[tid] = 0u; hcnt[tid + 256] = 0u;

    // ---- issue async copy of B-chunk 0 (codes 0..127) while we load A ----
#pragma unroll
    for (int r = 0; r < 4; ++r) {
        async_cp16(ebhi + (r * 256 + tid) * 8, &sbh[(r * 256 + wb) * 8]);
        async_cp16(eblo + (r * 256 + tid) * 8, &sbl[(r * 256 + wb) * 8]);
    }

    // ---- Load A (z, non-temporal: read-once stream), split to bf16 hi/lo,
    //      accumulate exact fp32 ||z||^2 partials ----
    // A-frag 32x32x16: m = lane&31, k = ks*16 + (lane>>5)*8 + j
    const float* zb = z + (size_t)b * (D * HW) + s0 + wb;
    short8 ahi0[4], alo0[4], ahi1[4], alo1[4];
    float zsq = 0.f;
#pragma unroll
    for (int ks = 0; ks < 4; ++ks) {
#pragma unroll
        for (int j = 0; j < 8; ++j) {
            size_t doff = (size_t)(ks * 16 + half * 8 + j) * HW;
            float v0 = __builtin_nontemporal_load(zb + doff + ln);
            float v1 = __builtin_nontemporal_load(zb + doff + 32 + ln);
            zsq = fmaf(v0, v0, zsq);
            zsq = fmaf(v1, v1, zsq);
            unsigned short h0 = bf16rne(v0);
            unsigned short l0 = bf16rne(v0 - __uint_as_float((unsigned)h0 << 16));
            unsigned short h1 = bf16rne(v1);
            unsigned short l1 = bf16rne(v1 - __uint_as_float((unsigned)h1 << 16));
            ahi0[ks][j] = (short)h0; alo0[ks][j] = (short)l0;
            ahi1[ks][j] = (short)h1; alo1[ks][j] = (short)l1;
        }
    }

    float best0[16], best1[16];
#pragma unroll
    for (int r = 0; r < 16; ++r) {
        best0[r] = __uint_as_float(0x7F800000u);
        best1[r] = __uint_as_float(0x7F800000u);
    }

    // ---- Main loop: 4 chunks x 4 tiles; single-buffered LDS, barriers overlap
    //      across the 3 co-resident blocks/CU ----
    for (int c = 0; c < 4; ++c) {
        __syncthreads();   // chunk-c copy complete (vmcnt drain at barrier)
#pragma unroll
        for (int tt = 0; tt < 4; ++tt) {
            float et = ee[(c * 4 + tt) * 32 + ln];
            short8 vbh[4], vbl[4];
#pragma unroll
            for (int ks = 0; ks < 4; ++ks) {
                vbh[ks] = *(const short8*)&sbh[tt * 2048 + ks * 512 + lane * 8];
                vbl[ks] = *(const short8*)&sbl[tt * 2048 + ks * 512 + lane * 8];
            }
            f32x16 acc0 = {0,0,0,0,0,0,0,0,0,0,0,0,0,0,0,0};
            f32x16 acc1 = {0,0,0,0,0,0,0,0,0,0,0,0,0,0,0,0};
#pragma unroll
            for (int ks = 0; ks < 4; ++ks) {
                acc0 = __builtin_amdgcn_mfma_f32_32x32x16_bf16(ahi0[ks], vbh[ks], acc0, 0, 0, 0);
                acc1 = __builtin_amdgcn_mfma_f32_32x32x16_bf16(ahi1[ks], vbh[ks], acc1, 0, 0, 0);
                acc0 = __builtin_amdgcn_mfma_f32_32x32x16_bf16(alo0[ks], vbh[ks], acc0, 0, 0, 0);
                acc1 = __builtin_amdgcn_mfma_f32_32x32x16_bf16(alo1[ks], vbh[ks], acc1, 0, 0, 0);
                acc0 = __builtin_amdgcn_mfma_f32_32x32x16_bf16(ahi0[ks], vbl[ks], acc0, 0, 0, 0);
                acc1 = __builtin_amdgcn_mfma_f32_32x32x16_bf16(ahi1[ks], vbl[ks], acc1, 0, 0, 0);
            }
            unsigned cb = (unsigned)((c * 4 + tt) * 32 + ln);
#pragma unroll
            for (int r = 0; r < 16; ++r) {
                float d0 = acc0[r] + et;
                float d1 = acc1[r] + et;
                float k0 = __uint_as_float((__float_as_uint(d0) & 0xFFFFFE00u) | cb);
                float k1 = __uint_as_float((__float_as_uint(d1) & 0xFFFFFE00u) | cb);
                best0[r] = fminf(best0[r], k0);
                best1[r] = fminf(best1[r], k1);
            }
        }
        __syncthreads();   // all waves done reading chunk c
        if (c < 3) {
#pragma unroll
            for (int r = 0; r < 4; ++r) {
                async_cp16(ebhi + (c + 1) * 8192 + (r * 256 + tid) * 8, &sbh[(r * 256 + wb) * 8]);
                async_cp16(eblo + (c + 1) * 8192 + (r * 256 + tid) * 8, &sbl[(r * 256 + wb) * 8]);
            }
        }
    }

    // ---- Cross-lane argmin (butterfly within 32-lane half) + SSE via
    //      SSE = sum ||z||^2 + sum bestd  (bestd = -2 z.e + ||e||^2, low bits masked) ----
    float lsse = zsq;
#pragma unroll
    for (int r = 0; r < 16; ++r) {
        float v0 = best0[r], v1 = best1[r];
#pragma unroll
        for (int m = 1; m < 32; m <<= 1) {
            v0 = fminf(v0, __shfl_xor(v0, m, 64));
            v1 = fminf(v1, __shfl_xor(v1, m, 64));
        }
        if (ln == r) {
            int row = (r & 3) + 8 * (r >> 2) + 4 * half;
            unsigned u0 = __float_as_uint(v0), u1 = __float_as_uint(v1);
            int c0 = (int)(u0 & 0x1FFu), c1 = (int)(u1 & 0x1FFu);
            bks[wb + row] = c0;
            bks[wb + 32 + row] = c1;
            atomicAdd(&hcnt[c0], 1u);
            atomicAdd(&hcnt[c1], 1u);
            lsse += __uint_as_float(u0 & 0xFFFFFE00u) + __uint_as_float(u1 & 0xFFFFFE00u);
        }
    }
#pragma unroll
    for (int off = 32; off > 0; off >>= 1) lsse += __shfl_down(lsse, off, 64);
    if (lane == 0) atomicAdd(sse_acc, lsse);

    __syncthreads();

    // ---- Epilogue: lane = pixel; gather exact E row (L2), z_q via NT stores
    //      (full-wave 256B contiguous per d; no L2 pollution) ----
    int bk = bks[tid];
    const float4* Er = (const float4*)(E + bk * D);
    float* ob = out + 1 + (size_t)b * (D * HW) + s0 + tid;
#pragma unroll
    for (int q = 0; q < 16; ++q) {
        float4 e4 = Er[q];
        __builtin_nontemporal_store(e4.x, ob + (size_t)(4 * q + 0) * HW);
        __builtin_nontemporal_store(e4.y, ob + (size_t)(4 * q + 1) * HW);
        __builtin_nontemporal_store(e4.z, ob + (size_t)(4 * q + 2) * HW);
        __builtin_nontemporal_store(e4.w, ob + (size_t)(4 * q + 3) * HW);
    }

    // ---- flush histogram ----
    unsigned hc0 = hcnt[tid], hc1 = hcnt[tid + 256];
    if (hc0) atomicAdd(&counts[tid], hc0);
    if (hc1) atomicAdd(&counts[tid + 256], hc1);

    // ---- fused finalize: last block computes loss + perplexity ----
    __syncthreads();
    if (tid == 0) {
        __threadfence();
        unsigned t = atomicAdd(ticket, 1u);
        sflag = (t == (unsigned)(NBLK - 1)) ? 1 : 0;
    }
    __syncthreads();
    if (sflag) {
        float c0f = (float)atomicAdd(&counts[tid], 0u);
        float c1f = (float)atomicAdd(&counts[tid + 256], 0u);
        float pa = c0f / (float)NPIX + 1e-10f;
        float pb = c1f / (float)NPIX + 1e-10f;
        float t = pa * logf(pa) + pb * logf(pb);
#pragma unroll
        for (int off = 32; off > 0; off >>= 1) t += __shfl_down(t, off, 64);
        if (lane == 0) red[wave] = t;
        __syncthreads();
        if (tid == 0) {
            float tot = red[0] + red[1] + red[2] + red[3];
            float s = atomicAdd(sse_acc, 0.0f);
            out[0] = (1.f + BETA) * s / (float)NELEM;
            out[out_size - 1] = expf(-tot);
        }
    }
}

extern "C" void kernel_launch(void* const* d_in, const int* in_sizes, int n_in,
                              void* d_out, int out_size, void* d_ws, size_t ws_size,
                              hipStream_t stream) {
    const float* z = (const float*)d_in[0];
    const float* E = (const float*)d_in[1];
    float* out = (float*)d_out;

    float* wsf = (float*)d_ws;
    float* sse = wsf;                                           // [0]
    unsigned int* ticket = (unsigned int*)(wsf + 1);            // [1]
    unsigned int* counts = (unsigned int*)(wsf + 4);            // 512 uints
    float* ee = wsf + 4 + K;                                    // 512 floats
    unsigned short* ebhi = (unsigned short*)(wsf + 4 + 2 * K);  // 32768 ushort (16B aligned)
    unsigned short* eblo = ebhi + K * D;                        // 32768 ushort

    prep_kernel<<<128, 256, 0, stream>>>(E, ee, ebhi, eblo, counts, sse, ticket);
    vq_mfma<<<NBLK, 256, 0, stream>>>(z, E, ee, ebhi, eblo, out, out_size, sse, counts, ticket);
}

// Round 5
// 195.649 us; speedup vs baseline: 1.1884x; 1.1884x over previous
//
#include <hip/hip_runtime.h>
#include <math.h>

constexpr int K = 512;
constexpr int D = 64;
constexpr int HW = 64 * 64;                      // 4096
constexpr int NPIX = 131072;
constexpr long long NELEM = (long long)NPIX * D; // 8388608
constexpr float BETA = 0.25f;
constexpr int PPB = 128;                         // pixels per block
constexpr int NBLK = NPIX / PPB;                 // 1024 blocks

typedef __attribute__((ext_vector_type(8))) short short8;
typedef __attribute__((ext_vector_type(16))) float f32x16;

__device__ inline unsigned short bf16rne(float x) {
    unsigned u = __float_as_uint(x);
    unsigned r = (u + 0x7FFFu + ((u >> 16) & 1u)) >> 16;
    return (unsigned short)r;
}

__device__ inline void async_cp16(const void* g, void* l) {
    __builtin_amdgcn_global_load_lds(
        (const __attribute__((address_space(1))) void*)g,
        (__attribute__((address_space(3))) void*)l, 16, 0, 0);
}

// E[n][k] -> bf16 hi/lo of -2E in MFMA-B frag order + exact fp32 ee[n].
// Also zeroes counts / sse / ticket (replaces a memset dispatch).
__global__ __launch_bounds__(256) void prep_kernel(
    const float* __restrict__ E, float* __restrict__ ee,
    unsigned short* __restrict__ ebhi, unsigned short* __restrict__ eblo,
    unsigned int* __restrict__ counts, float* __restrict__ sse,
    unsigned int* __restrict__ ticket) {
    int gid = blockIdx.x * 256 + threadIdx.x;   // 0..32767
    if (gid < K) counts[gid] = 0u;
    if (gid == K) { *sse = 0.f; *ticket = 0u; }
    int n = gid >> 6, k = gid & 63;
    float v = E[gid];
    float a = v * v;
#pragma unroll
    for (int off = 32; off > 0; off >>= 1) a += __shfl_down(a, off, 64);
    if ((threadIdx.x & 63) == 0) ee[n] = a;
    float m2 = -2.f * v;
    unsigned short hi = bf16rne(m2);
    unsigned short lo = bf16rne(m2 - __uint_as_float((unsigned)hi << 16));
    int idx = ((n >> 5) * 4 + (k >> 4)) * 512 + ((k >> 3) & 1) * 256 + (n & 31) * 8 + (k & 7);
    ebhi[idx] = hi;
    eblo[idx] = lo;
}

__global__ __launch_bounds__(256, 4) void vq_mfma(
    const float* __restrict__ z, const float* __restrict__ E,
    const float* __restrict__ ee, const unsigned short* __restrict__ ebhi,
    const unsigned short* __restrict__ eblo, float* __restrict__ out,
    int out_size, float* __restrict__ sse_acc,
    unsigned int* __restrict__ counts, unsigned int* __restrict__ ticket) {

    __shared__ __align__(16) unsigned short sbh[8192];  // 16 KB: 128-code chunk (hi)
    __shared__ __align__(16) unsigned short sbl[8192];  // 16 KB: (lo)
    __shared__ int bks[PPB];
    __shared__ unsigned int hcnt[K];
    __shared__ float red[4];
    __shared__ int sflag;

    const int tid = threadIdx.x;
    const int wave = tid >> 6;
    const int lane = tid & 63;
    const int ln = lane & 31;
    const int half = lane >> 5;
    const int wb = wave * 64;   // LDS-copy lane base (element groups)

    // XCD swizzle: XCD x (bid&7) owns 128 consecutive tiles = 4 whole images.
    const int tile = ((blockIdx.x & 7) << 7) | (blockIdx.x >> 3);
    const int p0 = tile * PPB;
    const int b = p0 >> 12;
    const int s0 = p0 & (HW - 1);
    const int wpix = s0 + wave * 32;            // this wave's 32 pixels

    hcnt[tid] = 0u; hcnt[tid + 256] = 0u;

    // ---- issue async copy of B-chunk 0 (codes 0..127) while we load A ----
#pragma unroll
    for (int r = 0; r < 4; ++r) {
        async_cp16(ebhi + (r * 256 + tid) * 8, &sbh[(r * 256 + wb) * 8]);
        async_cp16(eblo + (r * 256 + tid) * 8, &sbl[(r * 256 + wb) * 8]);
    }

    // ---- Load A (z) for this wave's 32-row tile, split to bf16 hi/lo ----
    // A-frag 32x32x16: m = lane&31, k = ks*16 + (lane>>5)*8 + j
    const float* zb = z + (size_t)b * (D * HW) + wpix;
    short8 ahi[4], alo[4];
    float zsq = 0.f;
#pragma unroll
    for (int ks = 0; ks < 4; ++ks) {
#pragma unroll
        for (int j = 0; j < 8; ++j) {
            float v = zb[(size_t)(ks * 16 + half * 8 + j) * HW + ln];
            zsq = fmaf(v, v, zsq);
            unsigned short h = bf16rne(v);
            unsigned short l = bf16rne(v - __uint_as_float((unsigned)h << 16));
            ahi[ks][j] = (short)h;
            alo[ks][j] = (short)l;
        }
    }

    float best[16];
#pragma unroll
    for (int r = 0; r < 16; ++r) best[r] = __uint_as_float(0x7F800000u);

    // ---- Main loop: 4 chunks x 4 tiles; single-buffered LDS ----
    for (int c = 0; c < 4; ++c) {
        __syncthreads();   // chunk-c copy complete
#pragma unroll
        for (int tt = 0; tt < 4; ++tt) {
            float et = ee[(c * 4 + tt) * 32 + ln];
            short8 vbh[4], vbl[4];
#pragma unroll
            for (int ks = 0; ks < 4; ++ks) {
                vbh[ks] = *(const short8*)&sbh[tt * 2048 + ks * 512 + lane * 8];
                vbl[ks] = *(const short8*)&sbl[tt * 2048 + ks * 512 + lane * 8];
            }
            f32x16 acc = {0,0,0,0,0,0,0,0,0,0,0,0,0,0,0,0};
#pragma unroll
            for (int ks = 0; ks < 4; ++ks) {
                acc = __builtin_amdgcn_mfma_f32_32x32x16_bf16(ahi[ks], vbh[ks], acc, 0, 0, 0);
                acc = __builtin_amdgcn_mfma_f32_32x32x16_bf16(alo[ks], vbh[ks], acc, 0, 0, 0);
                acc = __builtin_amdgcn_mfma_f32_32x32x16_bf16(ahi[ks], vbl[ks], acc, 0, 0, 0);
            }
            unsigned cb = (unsigned)((c * 4 + tt) * 32 + ln);
#pragma unroll
            for (int r = 0; r < 16; ++r) {
                float d = acc[r] + et;
                float kk = __uint_as_float((__float_as_uint(d) & 0xFFFFFE00u) | cb);
                best[r] = fminf(best[r], kk);
            }
        }
        __syncthreads();   // all waves done reading chunk c
        if (c < 3) {
#pragma unroll
            for (int r = 0; r < 4; ++r) {
                async_cp16(ebhi + (c + 1) * 8192 + (r * 256 + tid) * 8, &sbh[(r * 256 + wb) * 8]);
                async_cp16(eblo + (c + 1) * 8192 + (r * 256 + tid) * 8, &sbl[(r * 256 + wb) * 8]);
            }
        }
    }

    // ---- Cross-lane argmin (butterfly over 32 cols, within each half) ----
    // SSE = sum ||z||^2 + sum bestd  (bestd = -2 z.e + ||e||^2, low bits masked)
    float lsse = zsq;
#pragma unroll
    for (int r = 0; r < 16; ++r) {
        float v = best[r];
#pragma unroll
        for (int m = 1; m < 32; m <<= 1) v = fminf(v, __shfl_xor(v, m, 64));
        if (ln == r) {
            int row = (r & 3) + 8 * (r >> 2) + 4 * half;   // row within the 32-row tile
            unsigned u = __float_as_uint(v);
            int cw = (int)(u & 0x1FFu);
            bks[wave * 32 + row] = cw;
            atomicAdd(&hcnt[cw], 1u);
            lsse += __uint_as_float(u & 0xFFFFFE00u);
        }
    }
#pragma unroll
    for (int off = 32; off > 0; off >>= 1) lsse += __shfl_down(lsse, off, 64);
    if (lane == 0) atomicAdd(sse_acc, lsse);

    __syncthreads();

    // ---- Epilogue: thread -> (pixel = tid&127, d-half = tid>>7) ----
    int q = tid & (PPB - 1);
    int dh = tid >> 7;               // 0: d 0..31, 1: d 32..63
    int bk = bks[q];
    const float4* Er = (const float4*)(E + bk * D + dh * 32);
    float* ob = out + 1 + (size_t)b * (D * HW) + (size_t)dh * 32 * HW + s0 + q;
#pragma unroll
    for (int v4 = 0; v4 < 8; ++v4) {
        float4 e4 = Er[v4];
        ob[(size_t)(4 * v4 + 0) * HW] = e4.x;
        ob[(size_t)(4 * v4 + 1) * HW] = e4.y;
        ob[(size_t)(4 * v4 + 2) * HW] = e4.z;
        ob[(size_t)(4 * v4 + 3) * HW] = e4.w;
    }

    // ---- flush histogram ----
    unsigned hc0 = hcnt[tid], hc1 = hcnt[tid + 256];
    if (hc0) atomicAdd(&counts[tid], hc0);
    if (hc1) atomicAdd(&counts[tid + 256], hc1);

    // ---- fused finalize: last block computes loss + perplexity ----
    __syncthreads();
    if (tid == 0) {
        __threadfence();
        unsigned t = atomicAdd(ticket, 1u);
        sflag = (t == (unsigned)(NBLK - 1)) ? 1 : 0;
    }
    __syncthreads();
    if (sflag) {
        float c0f = (float)atomicAdd(&counts[tid], 0u);
        float c1f = (float)atomicAdd(&counts[tid + 256], 0u);
        float pa = c0f / (float)NPIX + 1e-10f;
        float pb = c1f / (float)NPIX + 1e-10f;
        float t = pa * logf(pa) + pb * logf(pb);
#pragma unroll
        for (int off = 32; off > 0; off >>= 1) t += __shfl_down(t, off, 64);
        if (lane == 0) red[wave] = t;
        __syncthreads();
        if (tid == 0) {
            float tot = red[0] + red[1] + red[2] + red[3];
            float s = atomicAdd(sse_acc, 0.0f);
            out[0] = (1.f + BETA) * s / (float)NELEM;
            out[out_size - 1] = expf(-tot);
        }
    }
}

extern "C" void kernel_launch(void* const* d_in, const int* in_sizes, int n_in,
                              void* d_out, int out_size, void* d_ws, size_t ws_size,
                              hipStream_t stream) {
    const float* z = (const float*)d_in[0];
    const float* E = (const float*)d_in[1];
    float* out = (float*)d_out;

    float* wsf = (float*)d_ws;
    float* sse = wsf;                                           // [0]
    unsigned int* ticket = (unsigned int*)(wsf + 1);            // [1]
    unsigned int* counts = (unsigned int*)(wsf + 4);            // 512 uints
    float* ee = wsf + 4 + K;                                    // 512 floats
    unsigned short* ebhi = (unsigned short*)(wsf + 4 + 2 * K);  // 32768 ushort (16B aligned)
    unsigned short* eblo = ebhi + K * D;                        // 32768 ushort

    prep_kernel<<<128, 256, 0, stream>>>(E, ee, ebhi, eblo, counts, sse, ticket);
    vq_mfma<<<NBLK, 256, 0, stream>>>(z, E, ee, ebhi, eblo, out, out_size, sse, counts, ticket);
}